// Round 5
// baseline (10460.255 us; speedup 1.0000x reference)
//
#include <hip/hip_runtime.h>
#include <cstdint>
#include <cstddef>

#define BATCH 16384

typedef float f32x4 __attribute__((ext_vector_type(4)));
typedef _Float16 f16x8 __attribute__((ext_vector_type(8)));

__device__ __forceinline__ unsigned short f2h_bits(float f) {
  _Float16 h = (_Float16)f;
  return __builtin_bit_cast(unsigned short, h);
}

// ===========================================================================
// Fragment-major layout: X'[row/16][k/8][r=row%16][c=k%8], halves.
// A wave's MFMA fragment (16 rows x 8 halves at chunk kc) is 256 B contiguous;
// a full 16x16x32 fragment load (4 quads -> 4 consecutive kc) is 1 KB
// contiguous with lane-linear addressing: off = tile*(K*16) + kk*512 + lane*8.
// K-loop does NO LDS and NO barriers: loads go straight to VGPRs with a
// 2-stage register pipeline; compiler emits vmcnt(N>0) instead of the
// barrier-forced vmcnt(0) drain that capped R2-R4 at ~3600 cyc/iter.
// ===========================================================================

// ---------------------------------------------------------------------------
// Hidden-layer GEMM: block 256x128 (4 wave-rows x RT=4, CT=8), output N=1024,
// written fragment-major (next layer's K=1024) via LDS transpose epilogue.
// ---------------------------------------------------------------------------
template <int RT, int CT, int K, bool RELU>
__launch_bounds__(256, 2)
__global__ void gemm_h(const unsigned short* __restrict__ A,
                       const unsigned short* __restrict__ Bw,
                       const float* __restrict__ Wfull,
                       const float* __restrict__ bias,
                       float tval,
                       unsigned short* __restrict__ Co) {
  constexpr int NI = K / 32;
  constexpr int BN = CT * 16;            // 128
  __shared__ unsigned short ctile[256 * 136];  // 256x128 tile, +8 pad
  __shared__ float biasLds[BN];

  const int tid = threadIdx.x;
  const int wave = tid >> 6;             // wave-row (WCOLS=1)
  const int lane = tid & 63;
  const int quad = lane >> 4;
  const int r16 = lane & 15;

  const int rowA0 = blockIdx.x * 256;
  const int rowB0 = blockIdx.y * BN;

  // effective bias = b[col] + t * W[col][K] (time-column fold)
  if (tid < BN) {
    const int col = rowB0 + tid;
    biasLds[tid] = bias[col] + tval * Wfull[(size_t)col * (K + 1) + K];
  }

  // per-fragment lane base pointers (halves)
  const unsigned short* aptr[RT];
#pragma unroll
  for (int mt = 0; mt < RT; ++mt)
    aptr[mt] = A + (size_t)(rowA0 / 16 + wave * RT + mt) * (K * 16) + lane * 8;
  const unsigned short* bptr[CT];
#pragma unroll
  for (int nt = 0; nt < CT; ++nt)
    bptr[nt] = Bw + (size_t)(rowB0 / 16 + nt) * (K * 16) + lane * 8;

  f32x4 acc[RT][CT];
  const f32x4 zero = {0.f, 0.f, 0.f, 0.f};
#pragma unroll
  for (int i = 0; i < RT; ++i)
#pragma unroll
    for (int j = 0; j < CT; ++j) acc[i][j] = zero;

  f16x8 af[2][RT], bf[2][CT];
  auto loadfr = [&](int kk, int s) {
#pragma unroll
    for (int mt = 0; mt < RT; ++mt)
      af[s][mt] = *(const f16x8*)(aptr[mt] + (size_t)kk * 512);
#pragma unroll
    for (int nt = 0; nt < CT; ++nt)
      bf[s][nt] = *(const f16x8*)(bptr[nt] + (size_t)kk * 512);
  };

  loadfr(0, 0);
#pragma unroll
  for (int kk = 0; kk < NI; ++kk) {
    const int cur = kk & 1;
    if (kk + 1 < NI) loadfr(kk + 1, cur ^ 1);  // stays in flight across MFMAs
#pragma unroll
    for (int mt = 0; mt < RT; ++mt)
#pragma unroll
      for (int nt = 0; nt < CT; ++nt)
        acc[mt][nt] = __builtin_amdgcn_mfma_f32_16x16x32_f16(
            af[cur][mt], bf[cur][nt], acc[mt][nt], 0, 0, 0);
  }

  __syncthreads();  // biasLds ready; ctile free

  // stage 1: bias+relu, fp16, into LDS tile (row-major, pad 136)
#pragma unroll
  for (int mt = 0; mt < RT; ++mt) {
    const int row0 = wave * (RT * 16) + mt * 16 + quad * 4;
#pragma unroll
    for (int nt = 0; nt < CT; ++nt) {
      const int col = nt * 16 + r16;
      const float bi = biasLds[col];
#pragma unroll
      for (int r = 0; r < 4; ++r) {
        float v = acc[mt][nt][r] + bi;
        if (RELU) v = fmaxf(v, 0.0f);
        ctile[(row0 + r) * 136 + col] = f2h_bits(v);
      }
    }
  }
  __syncthreads();

  // stage 2: read 16B fragment-chunks, store coalesced fragment-major
  // (output k-dim = 1024 -> 128 chunks per row-tile)
#pragma unroll
  for (int i = 0; i < 16; ++i) {
    const int chunk = i * 256 + tid;
    const int r = chunk & 15;
    const int kc = (chunk >> 4) & 15;
    const int mt2 = chunk >> 8;
    f16x8 vv = *(const f16x8*)(ctile + (mt2 * 16 + r) * 136 + kc * 8);
    *(f16x8*)(Co + ((size_t)(rowA0 / 16 + mt2) * 128 + (rowB0 / 8 + kc)) * 128 +
              r * 8) = vv;
  }
}

// ---------------------------------------------------------------------------
// Last layer (N=64) fused with RK4 combine. Block 32x64, waves 2x2, RT=1,
// CT=2, no-LDS K-loop. Epilogue: RK4 state update + yh written fragment-major
// (K=64) via small LDS transpose.
// ---------------------------------------------------------------------------
__launch_bounds__(256, 2)
__global__ void gemm_l4(const unsigned short* __restrict__ A,
                        const unsigned short* __restrict__ Bw,
                        const float* __restrict__ Wfull,
                        const float* __restrict__ bias,
                        float tval,
                        float* __restrict__ y, float* __restrict__ ksum,
                        unsigned short* __restrict__ yh,
                        float* __restrict__ outp, int mode, float dt) {
  constexpr int K = 1024, NI = K / 32;
  __shared__ unsigned short ytile[32 * 72];
  __shared__ float biasLds[64];

  const int tid = threadIdx.x;
  const int wave = tid >> 6;
  const int lane = tid & 63;
  const int quad = lane >> 4;
  const int r16 = lane & 15;

  const int rowA0 = blockIdx.x * 32;
  const int waveM = wave >> 1;
  const int waveN = wave & 1;

  if (tid < 64) {
    biasLds[tid] = bias[tid] + tval * Wfull[(size_t)tid * (K + 1) + K];
  }

  const unsigned short* aptr =
      A + (size_t)(rowA0 / 16 + waveM) * (K * 16) + lane * 8;
  const unsigned short* bptr[2];
#pragma unroll
  for (int nt = 0; nt < 2; ++nt)
    bptr[nt] = Bw + (size_t)(waveN * 2 + nt) * (K * 16) + lane * 8;

  f32x4 acc[2];
  const f32x4 zero = {0.f, 0.f, 0.f, 0.f};
  acc[0] = zero; acc[1] = zero;

  f16x8 af[2], bf[2][2];
  auto loadfr = [&](int kk, int s) {
    af[s] = *(const f16x8*)(aptr + (size_t)kk * 512);
#pragma unroll
    for (int nt = 0; nt < 2; ++nt)
      bf[s][nt] = *(const f16x8*)(bptr[nt] + (size_t)kk * 512);
  };

  loadfr(0, 0);
#pragma unroll
  for (int kk = 0; kk < NI; ++kk) {
    const int cur = kk & 1;
    if (kk + 1 < NI) loadfr(kk + 1, cur ^ 1);
#pragma unroll
    for (int nt = 0; nt < 2; ++nt)
      acc[nt] = __builtin_amdgcn_mfma_f32_16x16x32_f16(af[cur], bf[cur][nt],
                                                       acc[nt], 0, 0, 0);
  }

  __syncthreads();  // biasLds ready

  // RK4 combine + yh value into LDS tile
  const int lrow0 = waveM * 16 + quad * 4;
#pragma unroll
  for (int nt = 0; nt < 2; ++nt) {
    const int col = waveN * 32 + nt * 16 + r16;
    const float bi = biasLds[col];
#pragma unroll
    for (int r = 0; r < 4; ++r) {
      const float k = acc[nt][r] + bi;
      const int grow = rowA0 + lrow0 + r;
      const int idx = grow * 64 + col;
      const float yv = y[idx];
      float ynext;
      if (mode == 0) {
        ksum[idx] = k;
        ynext = yv + 0.5f * dt * k;
      } else if (mode == 1) {
        ksum[idx] += 2.f * k;
        ynext = yv + 0.5f * dt * k;
      } else if (mode == 2) {
        ksum[idx] += 2.f * k;
        ynext = yv + dt * k;
      } else {
        ynext = yv + (dt / 6.f) * (ksum[idx] + k);
        y[idx] = ynext;
        if (outp && col < 32) outp[grow * 32 + col] = ynext;
      }
      ytile[(lrow0 + r) * 72 + col] = f2h_bits(ynext);
    }
  }
  __syncthreads();

  // write yh fragment-major (K=64 -> 8 chunks per row-tile)
  {
    const int r = tid & 15;
    const int kc = (tid >> 4) & 7;
    const int mt2 = tid >> 7;
    f16x8 vv = *(const f16x8*)(ytile + (mt2 * 16 + r) * 72 + kc * 8);
    *(f16x8*)(yh + ((size_t)(rowA0 / 16 + mt2) * 8 + kc) * 128 + r * 8) = vv;
  }
}

// fp32 W (N x (K+1), time col dropped) -> fp16 fragment-major W'[n/16][k/8][16][8]
__global__ void conv_w(const float* __restrict__ W, unsigned short* __restrict__ Wh,
                       int N, int K) {
  const int idx = blockIdx.x * 256 + threadIdx.x;
  if (idx >= N * K) return;
  const int c = idx & 7;
  const int r = (idx >> 3) & 15;
  const int blk = idx >> 7;
  const int kc = blk % (K / 8);
  const int ntile = blk / (K / 8);
  Wh[idx] = f2h_bits(W[(size_t)(ntile * 16 + r) * (K + 1) + kc * 8 + c]);
}

// y0 = concat(x, aug): y row-major fp32, yh fragment-major fp16 (K=64)
__global__ void init_y(const float* __restrict__ x, const float* __restrict__ aug,
                       float* __restrict__ y, unsigned short* __restrict__ yh) {
  const int idx = blockIdx.x * 256 + threadIdx.x;  // BATCH*64
  const int c = idx & 7;
  const int r = (idx >> 3) & 15;
  const int kc = (idx >> 7) & 7;
  const int mtile = idx >> 10;
  const int i = mtile * 16 + r;
  const int j = kc * 8 + c;
  const float v = (j < 32) ? x[i * 32 + j] : aug[i * 32 + (j - 32)];
  yh[idx] = f2h_bits(v);
  y[i * 64 + j] = v;
}

extern "C" void kernel_launch(void* const* d_in, const int* in_sizes, int n_in,
                              void* d_out, int out_size, void* d_ws, size_t ws_size,
                              hipStream_t stream) {
  const float* x = (const float*)d_in[0];
  const float* aug = (const float*)d_in[1];
  const float* W[5];
  const float* b[5];
  for (int i = 0; i < 5; ++i) {
    W[i] = (const float*)d_in[2 + 2 * i];
    b[i] = (const float*)d_in[3 + 2 * i];
  }

  char* ws = (char*)d_ws;
  auto alloc = [&](size_t bytes) -> char* {
    char* p = ws;
    ws += (bytes + 255) & ~(size_t)255;
    return p;
  };
  float* y = (float*)alloc((size_t)BATCH * 64 * 4);
  unsigned short* yh = (unsigned short*)alloc((size_t)BATCH * 64 * 2);
  unsigned short* h1 = (unsigned short*)alloc((size_t)BATCH * 1024 * 2);
  unsigned short* h2 = (unsigned short*)alloc((size_t)BATCH * 1024 * 2);
  float* ksum = (float*)alloc((size_t)BATCH * 64 * 4);
  const int Kdim[5] = {64, 1024, 1024, 1024, 1024};
  const int Ndim[5] = {1024, 1024, 1024, 1024, 64};
  unsigned short* Wh[5];
  for (int i = 0; i < 5; ++i)
    Wh[i] = (unsigned short*)alloc((size_t)Ndim[i] * Kdim[i] * 2);

  for (int i = 0; i < 5; ++i) {
    const int total = Ndim[i] * Kdim[i];
    conv_w<<<(total + 255) / 256, 256, 0, stream>>>(W[i], Wh[i], Ndim[i], Kdim[i]);
  }
  init_y<<<BATCH * 64 / 256, 256, 0, stream>>>(x, aug, y, yh);

  const float dt = 0.125f;
  float* outp = (float*)d_out;

  auto eval = [&](float t, int mode, float* op) {
    // layer 0: [B,64] x [64,1024]^T -> h1 (fragment-major out)
    gemm_h<4, 8, 64, true>
        <<<dim3(BATCH / 256, 1024 / 128), 256, 0, stream>>>(
            yh, Wh[0], W[0], b[0], t, h1);
    unsigned short* src = h1;
    unsigned short* dst = h2;
    for (int L = 1; L <= 3; ++L) {
      gemm_h<4, 8, 1024, true>
          <<<dim3(BATCH / 256, 1024 / 128), 256, 0, stream>>>(
              src, Wh[L], W[L], b[L], t, dst);
      unsigned short* tmp = src; src = dst; dst = tmp;
    }
    // layer 4 + fused RK4 combine
    gemm_l4<<<dim3(BATCH / 32, 1), 256, 0, stream>>>(
        src, Wh[4], W[4], b[4], t, y, ksum, yh, op, mode, dt);
  };

  for (int s = 0; s < 8; ++s) {
    const float t0 = s * dt;
    eval(t0, 0, nullptr);
    eval(t0 + 0.5f * dt, 1, nullptr);
    eval(t0 + 0.5f * dt, 2, nullptr);
    eval(t0 + dt, 3, (s == 7) ? outp : nullptr);
  }
}

// Round 6
// 4493.392 us; speedup vs baseline: 2.3279x; 2.3279x over previous
//
#include <hip/hip_runtime.h>
#include <cstdint>
#include <cstddef>

#define BATCH 16384

typedef float f32x4 __attribute__((ext_vector_type(4)));
typedef _Float16 f16x8 __attribute__((ext_vector_type(8)));

__device__ __forceinline__ unsigned short f2h_bits(float f) {
  _Float16 h = (_Float16)f;
  return __builtin_bit_cast(unsigned short, h);
}

__device__ __forceinline__ void async_cp16(const void* g, void* l) {
  __builtin_amdgcn_global_load_lds(
      (const __attribute__((address_space(1))) unsigned int*)g,
      (__attribute__((address_space(3))) unsigned int*)l, 16, 0, 0);
}

// Barrier WITHOUT the full vmcnt(0) drain __syncthreads would force.
// Waits until only the newest 6 staging loads remain in flight.
#define PIPE_BAR_6() asm volatile("s_waitcnt vmcnt(6)\n\ts_barrier" ::: "memory")
#define PIPE_BAR_0() asm volatile("s_waitcnt vmcnt(0)\n\ts_barrier" ::: "memory")

// ---------------------------------------------------------------------------
// Hidden-layer GEMM, 3-stage software-pipelined LDS staging.
// C = relu(A[M,K] * Bw[N,K]^T + (bias + t*W[:,K])).
// Block 256x128, 4 waves 2x2, wave tile 128x64 (RT=8, CT=4), BK=32.
// Per stage each wave issues exactly 6 global_load_lds (A:4, B:2).
// K-loop iter k: wait vmcnt(6) [stage k done, stage k+1 STAYS IN FLIGHT],
// s_barrier, issue stage k+2, compute stage k. vmcnt never drains to 0
// until the peeled final iteration -> load latency finally hidden.
// XOR swizzle cp = c ^ ((row>>1)&3): frag ds_read_b128 2-way max (free).
// ---------------------------------------------------------------------------
template <int BM, int BN, int RT, int CT, int K, int N, bool RELU>
__launch_bounds__(256, 2)
__global__ void gemm_h(const unsigned short* __restrict__ A,
                       const unsigned short* __restrict__ Bw,
                       const float* __restrict__ Wfull,
                       const float* __restrict__ bias,
                       float tval,
                       unsigned short* __restrict__ Ch) {
  constexpr int BK = 32;
  constexpr int NI = K / BK;
  static_assert(NI >= 2, "pipeline needs >=2 stages");
  static_assert((BM * 4 + BN * 4) / 256 == 6, "vmcnt(6) assumes 6 loads/stage");
  __shared__ __align__(16) unsigned short smA[3][BM * BK];
  __shared__ __align__(16) unsigned short smB[3][BN * BK];
  __shared__ float biasLds[BN];

  const int tid = threadIdx.x;
  const int wave = tid >> 6;
  const int lane = tid & 63;
  const int quad = lane >> 4;
  const int r16 = lane & 15;

  const int rowA0 = blockIdx.x * BM;
  const int rowB0 = blockIdx.y * BN;
  const int waveM = wave >> 1;  // 2 wave-rows
  const int waveN = wave & 1;   // 2 wave-cols

  // effective bias = b[col] + t * W[col][K] (time-column fold).
  // Done BEFORE staging so its compiler-inserted vmcnt(0) is outside the loop.
  if (tid < BN) {
    const int col = rowB0 + tid;
    biasLds[tid] = bias[col] + tval * Wfull[(size_t)col * (K + 1) + K];
  }

  auto stage = [&](int k0, int buf) {
#pragma unroll
    for (int i = 0; i < BM * 4 / 256; ++i) {
      const int s = i * 256 + tid;                // LDS 16B-chunk position
      const int row = s >> 2;
      const int c = (s & 3) ^ ((row >> 1) & 3);   // global chunk (swizzled)
      const unsigned short* g = A + (size_t)(rowA0 + row) * K + (k0 + c * 8);
      char* l = ((char*)smA[buf]) + (size_t)(i * 256 + (wave << 6)) * 16;
      async_cp16(g, l);
    }
#pragma unroll
    for (int i = 0; i < BN * 4 / 256; ++i) {
      const int s = i * 256 + tid;
      const int row = s >> 2;
      const int c = (s & 3) ^ ((row >> 1) & 3);
      const unsigned short* g = Bw + (size_t)(rowB0 + row) * K + (k0 + c * 8);
      char* l = ((char*)smB[buf]) + (size_t)(i * 256 + (wave << 6)) * 16;
      async_cp16(g, l);
    }
  };

  f32x4 acc[RT][CT];
  const f32x4 zero = {0.f, 0.f, 0.f, 0.f};
#pragma unroll
  for (int i = 0; i < RT; ++i)
#pragma unroll
    for (int j = 0; j < CT; ++j) acc[i][j] = zero;

  auto compute = [&](int buf) {
    const unsigned short* sA = smA[buf];
    const unsigned short* sB = smB[buf];
    f16x8 af[RT], bfr[CT];
#pragma unroll
    for (int nt = 0; nt < CT; ++nt) {
      const int row = (waveN * CT + nt) * 16 + r16;
      const int cp = quad ^ ((row >> 1) & 3);
      bfr[nt] = *(const f16x8*)(sB + row * BK + cp * 8);
    }
#pragma unroll
    for (int mt = 0; mt < RT; ++mt) {
      const int row = (waveM * RT + mt) * 16 + r16;
      const int cp = quad ^ ((row >> 1) & 3);
      af[mt] = *(const f16x8*)(sA + row * BK + cp * 8);
    }
#pragma unroll
    for (int mt = 0; mt < RT; ++mt)
#pragma unroll
      for (int nt = 0; nt < CT; ++nt)
        acc[mt][nt] =
            __builtin_amdgcn_mfma_f32_16x16x32_f16(af[mt], bfr[nt], acc[mt][nt], 0, 0, 0);
  };

  stage(0, 0);
  stage(BK, 1);

#pragma unroll
  for (int kk = 0; kk < NI - 1; ++kk) {
    PIPE_BAR_6();  // stage kk complete; stage kk+1 still in flight
    if (kk + 2 < NI) stage((kk + 2) * BK, (kk + 2) % 3);
    compute(kk % 3);
  }
  PIPE_BAR_0();  // tail: drain the final stage
  compute((NI - 1) % 3);

  // epilogue: C/D layout col=lane&15, row=(lane>>4)*4+r
#pragma unroll
  for (int mt = 0; mt < RT; ++mt) {
    const int grow0 = rowA0 + (waveM * RT + mt) * 16 + quad * 4;
#pragma unroll
    for (int nt = 0; nt < CT; ++nt) {
      const int lcol = (waveN * CT + nt) * 16 + r16;
      const int gcol = rowB0 + lcol;
      const float bi = biasLds[lcol];
#pragma unroll
      for (int r = 0; r < 4; ++r) {
        float v = acc[mt][nt][r] + bi;
        if (RELU) v = fmaxf(v, 0.0f);
        Ch[(size_t)(grow0 + r) * N + gcol] = f2h_bits(v);
      }
    }
  }
}

// ---------------------------------------------------------------------------
// Last layer fused with RK4 combine (BM=32, BN=64 full width), dbuf BK=32.
// (Unchanged from R4 -- not the bottleneck this round.)
// ---------------------------------------------------------------------------
__launch_bounds__(256, 4)
__global__ void gemm_l4(const unsigned short* __restrict__ A,
                        const unsigned short* __restrict__ Bw,
                        const float* __restrict__ Wfull,
                        const float* __restrict__ bias,
                        float tval,
                        float* __restrict__ y, float* __restrict__ ksum,
                        unsigned short* __restrict__ yh,
                        float* __restrict__ outp, int mode, float dt) {
  constexpr int K = 1024, BK = 32, BM = 32, BN = 64, NI = K / BK;
  __shared__ __align__(16) unsigned short smA[2][BM * BK];
  __shared__ __align__(16) unsigned short smB[2][BN * BK];
  __shared__ float biasLds[BN];

  const int tid = threadIdx.x;
  const int wave = tid >> 6;
  const int lane = tid & 63;
  const int quad = lane >> 4;
  const int r16 = lane & 15;

  const int rowA0 = blockIdx.x * BM;
  const int waveM = wave >> 1;
  const int waveN = wave & 1;

  if (tid < BN) {
    biasLds[tid] = bias[tid] + tval * Wfull[(size_t)tid * (K + 1) + K];
  }

  auto stage = [&](int k0, int buf) {
    if (tid < BM * 4) {  // A: 128 chunks
      const int s = tid;
      const int row = s >> 2;
      const int c = (s & 3) ^ ((row >> 1) & 3);
      const unsigned short* g = A + (size_t)(rowA0 + row) * K + (k0 + c * 8);
      char* l = ((char*)smA[buf]) + (size_t)(wave << 6) * 16;
      async_cp16(g, l);
    }
    {  // B: 256 chunks
      const int s = tid;
      const int row = s >> 2;
      const int c = (s & 3) ^ ((row >> 1) & 3);
      const unsigned short* g = Bw + (size_t)row * K + (k0 + c * 8);
      char* l = ((char*)smB[buf]) + (size_t)(wave << 6) * 16;
      async_cp16(g, l);
    }
  };

  f32x4 acc[2];
  const f32x4 zero = {0.f, 0.f, 0.f, 0.f};
  acc[0] = zero; acc[1] = zero;

  stage(0, 0);

#pragma unroll 2
  for (int kk = 0; kk < NI; ++kk) {
    __syncthreads();
    if (kk + 1 < NI) stage((kk + 1) * BK, (kk + 1) & 1);

    const unsigned short* sA = smA[kk & 1];
    const unsigned short* sB = smB[kk & 1];
    f16x8 af, bfr[2];
    {
      const int row = waveM * 16 + r16;
      const int cp = quad ^ ((row >> 1) & 3);
      af = *(const f16x8*)(sA + row * BK + cp * 8);
    }
#pragma unroll
    for (int nt = 0; nt < 2; ++nt) {
      const int row = (waveN * 2 + nt) * 16 + r16;
      const int cp = quad ^ ((row >> 1) & 3);
      bfr[nt] = *(const f16x8*)(sB + row * BK + cp * 8);
    }
#pragma unroll
    for (int nt = 0; nt < 2; ++nt)
      acc[nt] = __builtin_amdgcn_mfma_f32_16x16x32_f16(af, bfr[nt], acc[nt], 0, 0, 0);
  }

  // epilogue + fused RK4 combine
  const int grow0 = rowA0 + waveM * 16 + quad * 4;
#pragma unroll
  for (int nt = 0; nt < 2; ++nt) {
    const int col = waveN * 32 + nt * 16 + r16;
    const float bi = biasLds[col];
#pragma unroll
    for (int r = 0; r < 4; ++r) {
      const float k = acc[nt][r] + bi;
      const int row = grow0 + r;
      const int idx = row * 64 + col;
      if (mode == 0) {
        ksum[idx] = k;
        yh[idx] = f2h_bits(y[idx] + 0.5f * dt * k);
      } else if (mode == 1) {
        ksum[idx] += 2.f * k;
        yh[idx] = f2h_bits(y[idx] + 0.5f * dt * k);
      } else if (mode == 2) {
        ksum[idx] += 2.f * k;
        yh[idx] = f2h_bits(y[idx] + dt * k);
      } else {
        const float yn = y[idx] + (dt / 6.f) * (ksum[idx] + k);
        y[idx] = yn;
        yh[idx] = f2h_bits(yn);
        if (outp && col < 32) outp[row * 32 + col] = yn;
      }
    }
  }
}

// fp32 W (N x (K+1), time col dropped) -> fp16 Wh (N x K), row-major
__global__ void conv_w(const float* __restrict__ W, unsigned short* __restrict__ Wh,
                       int N, int K) {
  const int idx = blockIdx.x * 256 + threadIdx.x;
  if (idx < N * K) {
    const int n = idx / K;
    const int k = idx - n * K;
    Wh[idx] = f2h_bits(W[(size_t)n * (K + 1) + k]);
  }
}

// y0 = concat(x, aug); row-major fp32 + fp16 copy
__global__ void init_y(const float* __restrict__ x, const float* __restrict__ aug,
                       float* __restrict__ y, unsigned short* __restrict__ yh) {
  const int idx = blockIdx.x * 256 + threadIdx.x;  // BATCH*64
  const int i = idx >> 6;
  const int j = idx & 63;
  const float v = (j < 32) ? x[i * 32 + j] : aug[i * 32 + (j - 32)];
  y[idx] = v;
  yh[idx] = f2h_bits(v);
}

extern "C" void kernel_launch(void* const* d_in, const int* in_sizes, int n_in,
                              void* d_out, int out_size, void* d_ws, size_t ws_size,
                              hipStream_t stream) {
  const float* x = (const float*)d_in[0];
  const float* aug = (const float*)d_in[1];
  const float* W[5];
  const float* b[5];
  for (int i = 0; i < 5; ++i) {
    W[i] = (const float*)d_in[2 + 2 * i];
    b[i] = (const float*)d_in[3 + 2 * i];
  }

  char* ws = (char*)d_ws;
  auto alloc = [&](size_t bytes) -> char* {
    char* p = ws;
    ws += (bytes + 255) & ~(size_t)255;
    return p;
  };
  float* y = (float*)alloc((size_t)BATCH * 64 * 4);
  unsigned short* yh = (unsigned short*)alloc((size_t)BATCH * 64 * 2);
  unsigned short* h1 = (unsigned short*)alloc((size_t)BATCH * 1024 * 2);
  unsigned short* h2 = (unsigned short*)alloc((size_t)BATCH * 1024 * 2);
  float* ksum = (float*)alloc((size_t)BATCH * 64 * 4);
  const int Kdim[5] = {64, 1024, 1024, 1024, 1024};
  const int Ndim[5] = {1024, 1024, 1024, 1024, 64};
  unsigned short* Wh[5];
  for (int i = 0; i < 5; ++i)
    Wh[i] = (unsigned short*)alloc((size_t)Ndim[i] * Kdim[i] * 2);

  for (int i = 0; i < 5; ++i) {
    const int total = Ndim[i] * Kdim[i];
    conv_w<<<(total + 255) / 256, 256, 0, stream>>>(W[i], Wh[i], Ndim[i], Kdim[i]);
  }
  init_y<<<BATCH * 64 / 256, 256, 0, stream>>>(x, aug, y, yh);

  const float dt = 0.125f;
  float* outp = (float*)d_out;

  auto eval = [&](float t, int mode, float* op) {
    // layer 0: [B,64] x [64,1024]^T -> h1
    gemm_h<256, 128, 8, 4, 64, 1024, true>
        <<<dim3(BATCH / 256, 1024 / 128), 256, 0, stream>>>(
            yh, Wh[0], W[0], b[0], t, h1);
    unsigned short* src = h1;
    unsigned short* dst = h2;
    for (int L = 1; L <= 3; ++L) {
      gemm_h<256, 128, 8, 4, 1024, 1024, true>
          <<<dim3(BATCH / 256, 1024 / 128), 256, 0, stream>>>(
              src, Wh[L], W[L], b[L], t, dst);
      unsigned short* tmp = src; src = dst; dst = tmp;
    }
    gemm_l4<<<dim3(BATCH / 32, 1), 256, 0, stream>>>(
        src, Wh[4], W[4], b[4], t, y, ksum, yh, op, mode, dt);
  };

  for (int s = 0; s < 8; ++s) {
    const float t0 = s * dt;
    eval(t0, 0, nullptr);
    eval(t0 + 0.5f * dt, 1, nullptr);
    eval(t0 + 0.5f * dt, 2, nullptr);
    eval(t0 + dt, 3, (s == 7) ? outp : nullptr);
  }
}